// Round 3
// baseline (3649.129 us; speedup 1.0000x reference)
//
#include <hip/hip_runtime.h>
#include <hip/hip_bf16.h>

// Fused transformer block, one 4-wave workgroup per batch element.
// h / h2 / x2 are parked in the block's own 64KB region of d_out (bf16), so
// LDS is only 32KB -> 4 blocks/CU at VGPR<=128 (launch_bounds(256,4): 2nd arg
// behaves as min-blocks/CU; 512-VGPR/SIMD occupancy file => cap 128).
// ws layout (bf16/ushort): [0,65536) WqT[h][d][c]; [65536,131072) WkT;
// [131072,196608) WvT; [196608,262144) WprojT[n][c]; [262144,524288) W1T[n][c];
// [524288,786432) W2T[n][k].  Requires ws_size >= 1572864 bytes.

typedef float v4f __attribute__((ext_vector_type(4)));
typedef int   v4i __attribute__((ext_vector_type(4)));
typedef float f4v __attribute__((ext_vector_type(4)));

#define DEV static __device__ __forceinline__

DEV unsigned short f2bf(float f){
  return __builtin_bit_cast(unsigned short, __float2bfloat16(f));
}
DEV float bf2f(unsigned short u){
  unsigned v = (unsigned)u << 16;
  return __builtin_bit_cast(float, v);
}

// bf16 MFMA via inline asm: layout-safe under consistent per-lane contiguous-8
// K fragments (A from [M][K] rows, B from [N][K] rows i.e. pre-transposed).
DEV v4f mfma16(v4i a, v4i b, v4f c){
  asm("v_mfma_f32_16x16x32_bf16 %0, %1, %2, %0" : "+v"(c) : "v"(a), "v"(b));
  return c;
}
// Hazard fence: asm MFMA is opaque to the hazard recognizer.
DEV v4f accfence(v4f c){
  asm("s_nop 7\n\ts_nop 3" : "+v"(c));
  return c;
}

// Swizzled LDS byte offsets (G4: XOR row bits into 16B-granule bits).
DEV int koff(int r, int c){ return r*128 + ((c*2) ^ ((r & 7) << 4)); }   // [*][64]  bf16
DEV int aoff(int r, int c){ return r*256 + ((c*2) ^ ((r & 7) << 4)); }   // [64][128] bf16

DEV unsigned long long pack4(v4f v){
  return (unsigned long long)f2bf(v[0])
       | ((unsigned long long)f2bf(v[1]) << 16)
       | ((unsigned long long)f2bf(v[2]) << 32)
       | ((unsigned long long)f2bf(v[3]) << 48);
}

DEV float rsum64(float v){
  #pragma unroll
  for (int k = 1; k < 64; k <<= 1) v += __shfl_xor(v, k);
  return v;
}
DEV float rsum16(float v){
  #pragma unroll
  for (int k = 1; k < 16; k <<= 1) v += __shfl_xor(v, k);
  return v;
}
DEV float rmax16(float v){
  #pragma unroll
  for (int k = 1; k < 16; k <<= 1) v = fmaxf(v, __shfl_xor(v, k));
  return v;
}

__global__ void prep_w(const float* __restrict__ Wq, const float* __restrict__ Wk,
                       const float* __restrict__ Wv, const float* __restrict__ Wp,
                       const float* __restrict__ W1, const float* __restrict__ W2,
                       unsigned short* __restrict__ ws){
  int t = blockIdx.x * 256 + threadIdx.x;   // grid covers exactly 786432
  float v;
  if (t < 196608){
    int seg = t >> 16, r = t & 65535;
    int c = r & 255, d = (r >> 8) & 63, h = r >> 14;
    const float* W = (seg == 0) ? Wq : ((seg == 1) ? Wk : Wv);
    v = W[h*16384 + c*64 + d];
  } else if (t < 262144){
    int r = t - 196608; int n = r >> 8, c = r & 255;
    v = Wp[c*256 + n];
  } else if (t < 524288){
    int r = t - 262144; int n = r >> 8, c = r & 255;
    v = W1[c*1024 + n];
  } else {
    int r = t - 524288; int n = r >> 10, k = r & 1023;
    v = W2[k*256 + n];
  }
  ws[t] = f2bf(v);
}

__global__ __launch_bounds__(256, 4) void blk_fwd(
    const float* __restrict__ x,
    const float* __restrict__ ln1g, const float* __restrict__ ln1b,
    const unsigned short* __restrict__ wqT,
    const unsigned short* __restrict__ wkT,
    const unsigned short* __restrict__ wvT,
    const unsigned short* __restrict__ wpT,
    const float* __restrict__ bpj,
    const float* __restrict__ ln2g, const float* __restrict__ ln2b,
    const unsigned short* __restrict__ w1T,
    const float* __restrict__ b1,
    const unsigned short* __restrict__ w2T,
    const float* __restrict__ b2,
    float* __restrict__ out)
{
  __shared__ char smb[32768] __attribute__((aligned(16)));
  char* sm = smb;
  // Phase B: QLS=q, KLS=k, VTLS=v^T, PATLS = per-wave P/att stripes (2K each).
  // Phase C: PSUM/PSQ/MU2/RS2 alias QLS.  Phase D: ALS [64][128] aliases QLS+KLS.
  const int QLS = 0, KLS = 8192, VTLS = 16384, PATLS = 24576;
  const int PSUM = 0, PSQ = 1024, MU2 = 2048, RS2 = 2304;
  const int ALS = 0;

  const int b = blockIdx.x;
  const float* __restrict__ xb   = x   + (size_t)b * (64*256);
  float* __restrict__       outb = out + (size_t)b * (64*256);
  unsigned short* hbuf  = (unsigned short*)outb;   // h, then h2 (bytes [0,32K))
  unsigned short* x2buf = hbuf + 16384;            // x2 bf16    (bytes [32K,64K))
  const int tid = threadIdx.x;
  const int w = tid >> 6, l = tid & 63, m = l & 15, g = l >> 4;
  const v4f zf = {0.f, 0.f, 0.f, 0.f};

  // ---------------- Phase A: LN1 -> h (bf16, parked in d_out region) ----------
  {
    f4v lg = *(const f4v*)(ln1g + 4*l);
    f4v lb = *(const f4v*)(ln1b + 4*l);
    #pragma unroll
    for (int rr = 0; rr < 16; ++rr){
      int r = w*16 + rr;
      f4v xv = *(const f4v*)(xb + r*256 + 4*l);
      float s = xv[0]+xv[1]+xv[2]+xv[3];
      float q = xv[0]*xv[0]+xv[1]*xv[1]+xv[2]*xv[2]+xv[3]*xv[3];
      s = rsum64(s); q = rsum64(q);
      float mu = s * (1.f/256.f);
      float rs = rsqrtf(q * (1.f/256.f) - mu*mu + 1e-6f);
      unsigned long long pk = 0;
      #pragma unroll
      for (int j = 0; j < 4; ++j){
        float hv = (xv[j] - mu) * rs * lg[j] + lb[j];
        pk |= (unsigned long long)f2bf(hv) << (16*j);
      }
      *(unsigned long long*)(hbuf + r*256 + 4*l) = pk;
    }
  }
  __syncthreads();   // compiler drains vmcnt before s_barrier -> h visible via L2

  // ---------------- Phase B: attention; sa accumulated in regs ----------------
  v4f sa[4][4];
  #pragma unroll
  for (int i = 0; i < 4; ++i){
    #pragma unroll
    for (int j = 0; j < 4; ++j) sa[i][j] = zf;
  }

  #pragma unroll 1
  for (int hh = 0; hh < 4; ++hh){
    // v-pass: wave w owns d-cols 16w..16w+15, all 64 rows -> v^T in LDS
    {
      const unsigned short* bsrc = wvT + hh*16384 + (w*16 + m)*256;
      v4f va[4] = {zf, zf, zf, zf};
      #pragma unroll
      for (int ks = 0; ks < 8; ++ks){
        int k0 = ks*32 + 8*g;
        v4i bfr = *(const v4i*)(bsrc + k0);
        #pragma unroll
        for (int rt = 0; rt < 4; ++rt){
          v4i af = *(const v4i*)(hbuf + (rt*16 + m)*256 + k0);
          va[rt] = mfma16(af, bfr, va[rt]);
        }
      }
      #pragma unroll
      for (int rt = 0; rt < 4; ++rt){
        va[rt] = accfence(va[rt]);
        *(unsigned long long*)(sm + VTLS + koff(w*16 + m, rt*16 + 4*g)) = pack4(va[rt]);
      }
    }
    // q,k-pass (shared A-fragments)
    {
      const unsigned short* bq = wqT + hh*16384 + (w*16 + m)*256;
      const unsigned short* bk = wkT + hh*16384 + (w*16 + m)*256;
      v4f qa[4] = {zf, zf, zf, zf};
      v4f ka[4] = {zf, zf, zf, zf};
      #pragma unroll
      for (int ks = 0; ks < 8; ++ks){
        int k0 = ks*32 + 8*g;
        v4i bq4 = *(const v4i*)(bq + k0);
        v4i bk4 = *(const v4i*)(bk + k0);
        #pragma unroll
        for (int rt = 0; rt < 4; ++rt){
          v4i af = *(const v4i*)(hbuf + (rt*16 + m)*256 + k0);
          qa[rt] = mfma16(af, bq4, qa[rt]);
          ka[rt] = mfma16(af, bk4, ka[rt]);
        }
      }
      #pragma unroll
      for (int rt = 0; rt < 4; ++rt){
        qa[rt] = accfence(qa[rt]); ka[rt] = accfence(ka[rt]);
        #pragma unroll
        for (int j = 0; j < 4; ++j){
          *(unsigned short*)(sm + QLS + koff(rt*16 + 4*g + j, w*16 + m)) = f2bf(qa[rt][j]);
          *(unsigned short*)(sm + KLS + koff(rt*16 + 4*g + j, w*16 + m)) = f2bf(ka[rt][j]);
        }
      }
    }
    __syncthreads();   // bar1: q,k,v^T ready; prev-head PATLS readers done

    // S = Q K^T for stripe rows w*16..w*16+15; softmax; P -> own PATLS stripe
    {
      v4f s4[4] = {zf, zf, zf, zf};
      #pragma unroll
      for (int ks = 0; ks < 2; ++ks){
        int k0 = ks*32 + 8*g;
        v4i qf = *(const v4i*)(sm + QLS + koff(w*16 + m, k0));
        #pragma unroll
        for (int nt = 0; nt < 4; ++nt){
          v4i kf = *(const v4i*)(sm + KLS + koff(nt*16 + m, k0));
          s4[nt] = mfma16(qf, kf, s4[nt]);
        }
      }
      #pragma unroll
      for (int nt = 0; nt < 4; ++nt) s4[nt] = accfence(s4[nt]);
      float mx[4] = {-3e38f, -3e38f, -3e38f, -3e38f};
      #pragma unroll
      for (int nt = 0; nt < 4; ++nt){
        #pragma unroll
        for (int j = 0; j < 4; ++j){
          int t = w*16 + 4*g + j, ss = nt*16 + m;
          float z = s4[nt][j] * 0.125f;
          z = (ss <= t) ? z : -1e30f;
          s4[nt][j] = z;
          mx[j] = fmaxf(mx[j], z);
        }
      }
      #pragma unroll
      for (int j = 0; j < 4; ++j) mx[j] = rmax16(mx[j]);
      float sum[4] = {0.f, 0.f, 0.f, 0.f};
      #pragma unroll
      for (int nt = 0; nt < 4; ++nt){
        #pragma unroll
        for (int j = 0; j < 4; ++j){
          float p = __expf(s4[nt][j] - mx[j]);
          s4[nt][j] = p;
          sum[j] += p;
        }
      }
      #pragma unroll
      for (int j = 0; j < 4; ++j) sum[j] = 1.f / rsum16(sum[j]);
      #pragma unroll
      for (int nt = 0; nt < 4; ++nt){
        #pragma unroll
        for (int j = 0; j < 4; ++j)
          *(unsigned short*)(sm + PATLS + w*2048 + koff(4*g + j, nt*16 + m)) =
              f2bf(s4[nt][j] * sum[j]);
      }
    }

    // PV: att rows w*16..w*16+15 -> overwrite own P stripe (same-wave LDS order)
    {
      v4f av[4] = {zf, zf, zf, zf};
      #pragma unroll
      for (int ks = 0; ks < 2; ++ks){
        int k0 = ks*32 + 8*g;
        v4i pf = *(const v4i*)(sm + PATLS + w*2048 + koff(m, k0));
        #pragma unroll
        for (int nt = 0; nt < 4; ++nt){
          v4i vf = *(const v4i*)(sm + VTLS + koff(nt*16 + m, k0));
          av[nt] = mfma16(pf, vf, av[nt]);
        }
      }
      #pragma unroll
      for (int nt = 0; nt < 4; ++nt) av[nt] = accfence(av[nt]);
      #pragma unroll
      for (int nt = 0; nt < 4; ++nt){
        #pragma unroll
        for (int j = 0; j < 4; ++j)
          *(unsigned short*)(sm + PATLS + w*2048 + koff(4*g + j, nt*16 + m)) =
              f2bf(av[nt][j]);
      }
    }
    __syncthreads();   // bar2: att ready for all-stripe proj reads

    // proj: sa += att_head @ Wproj[64*hh:, :]; wave w owns cols w*64..w*64+63
    #pragma unroll
    for (int ks = 0; ks < 2; ++ks){
      int k0 = ks*32 + 8*g;
      v4i af2[4];
      #pragma unroll
      for (int rt = 0; rt < 4; ++rt)
        af2[rt] = *(const v4i*)(sm + PATLS + rt*2048 + koff(m, k0));
      #pragma unroll
      for (int nt = 0; nt < 4; ++nt){
        v4i bp = *(const v4i*)(wpT + (w*64 + nt*16 + m)*256 + hh*64 + k0);
        #pragma unroll
        for (int rt = 0; rt < 4; ++rt) sa[rt][nt] = mfma16(af2[rt], bp, sa[rt][nt]);
      }
    }
    // no barrier: next head's q/k/v writes are protected by bar1; PATLS by next bar1
  }

  // ---------------- Phase C: x2 = x + sa + bproj (park bf16); LN2 -> h2 --------
  {
    #pragma unroll
    for (int i = 0; i < 4; ++i){
      #pragma unroll
      for (int j = 0; j < 4; ++j) sa[i][j] = accfence(sa[i][j]);
    }
    float bp4[4], lg2[4], lb2[4];
    #pragma unroll
    for (int nt = 0; nt < 4; ++nt){
      int cc = w*64 + nt*16 + m;
      bp4[nt] = bpj[cc]; lg2[nt] = ln2g[cc]; lb2[nt] = ln2b[cc];
    }
    #pragma unroll
    for (int rt = 0; rt < 4; ++rt){
      #pragma unroll
      for (int j = 0; j < 4; ++j){
        int row = rt*16 + 4*g + j;
        #pragma unroll
        for (int nt = 0; nt < 4; ++nt){
          int col = w*64 + nt*16 + m;
          float v = xb[row*256 + col] + sa[rt][nt][j] + bp4[nt];
          sa[rt][nt][j] = v;
          x2buf[row*256 + col] = f2bf(v);
        }
      }
    }
    #pragma unroll
    for (int rt = 0; rt < 4; ++rt){
      #pragma unroll
      for (int j = 0; j < 4; ++j){
        float s = 0.f, q = 0.f;
        #pragma unroll
        for (int nt = 0; nt < 4; ++nt){ float v = sa[rt][nt][j]; s += v; q += v*v; }
        s = rsum16(s); q = rsum16(q);
        if (m == 0){
          int row = rt*16 + 4*g + j;
          *(float*)(sm + PSUM + (w*64 + row)*4) = s;   // aliases dead QLS
          *(float*)(sm + PSQ  + (w*64 + row)*4) = q;
        }
      }
    }
    __syncthreads();
    if (tid < 64){
      float s = 0.f, q = 0.f;
      #pragma unroll
      for (int i = 0; i < 4; ++i){
        s += *(const float*)(sm + PSUM + (i*64 + tid)*4);
        q += *(const float*)(sm + PSQ  + (i*64 + tid)*4);
      }
      float mu = s * (1.f/256.f);
      float rs = rsqrtf(q * (1.f/256.f) - mu*mu + 1e-6f);
      *(float*)(sm + MU2 + tid*4) = mu;
      *(float*)(sm + RS2 + tid*4) = rs;
    }
    __syncthreads();
    #pragma unroll
    for (int rt = 0; rt < 4; ++rt){
      #pragma unroll
      for (int j = 0; j < 4; ++j){
        int row = rt*16 + 4*g + j;
        float mu = *(const float*)(sm + MU2 + row*4);
        float rs = *(const float*)(sm + RS2 + row*4);
        #pragma unroll
        for (int nt = 0; nt < 4; ++nt){
          int col = w*64 + nt*16 + m;
          float h2 = (sa[rt][nt][j] - mu) * rs * lg2[nt] + lb2[nt];
          hbuf[row*256 + col] = f2bf(h2);   // overwrites h (dead)
        }
      }
    }
  }
  __syncthreads();   // h2 stores drained to L2
  __threadfence();   // invalidate L1 so h2 re-reads don't hit stale h lines

  // ---------------- Phase D: MLP, 8 chunks of 128 cols; ff in regs ------------
  v4f ff[4][4];
  #pragma unroll
  for (int i = 0; i < 4; ++i){
    #pragma unroll
    for (int j = 0; j < 4; ++j) ff[i][j] = zf;
  }

  #pragma unroll 1
  for (int ch = 0; ch < 8; ++ch){
    v4f a1[4][2];
    #pragma unroll
    for (int i = 0; i < 4; ++i){ a1[i][0] = zf; a1[i][1] = zf; }
    #pragma unroll
    for (int ks = 0; ks < 8; ++ks){
      int k0 = ks*32 + 8*g;
      v4i bw0 = *(const v4i*)(w1T + (ch*128 + w*32 +      m)*256 + k0);
      v4i bw1 = *(const v4i*)(w1T + (ch*128 + w*32 + 16 + m)*256 + k0);
      #pragma unroll
      for (int rt = 0; rt < 4; ++rt){
        v4i af = *(const v4i*)(hbuf + (rt*16 + m)*256 + k0);
        a1[rt][0] = mfma16(af, bw0, a1[rt][0]);
        a1[rt][1] = mfma16(af, bw1, a1[rt][1]);
      }
    }
    float b1v[2] = { b1[ch*128 + w*32 + m], b1[ch*128 + w*32 + 16 + m] };
    #pragma unroll
    for (int i = 0; i < 4; ++i){ a1[i][0] = accfence(a1[i][0]); a1[i][1] = accfence(a1[i][1]); }
    #pragma unroll
    for (int rt = 0; rt < 4; ++rt){
      #pragma unroll
      for (int j = 0; j < 4; ++j){
        int row = rt*16 + 4*g + j;
        #pragma unroll
        for (int nt = 0; nt < 2; ++nt){
          float v = fmaxf(a1[rt][nt][j] + b1v[nt], 0.f);
          *(unsigned short*)(sm + ALS + aoff(row, w*32 + nt*16 + m)) = f2bf(v);
        }
      }
    }
    __syncthreads();
    #pragma unroll
    for (int ks = 0; ks < 4; ++ks){
      int k0 = ks*32 + 8*g;
      v4i af[4];
      #pragma unroll
      for (int rt = 0; rt < 4; ++rt)
        af[rt] = *(const v4i*)(sm + ALS + aoff(rt*16 + m, k0));
      #pragma unroll
      for (int nt = 0; nt < 4; ++nt){
        v4i bw = *(const v4i*)(w2T + (w*64 + nt*16 + m)*1024 + ch*128 + k0);
        #pragma unroll
        for (int rt = 0; rt < 4; ++rt) ff[rt][nt] = mfma16(af[rt], bw, ff[rt][nt]);
      }
    }
    __syncthreads();
  }

  // ---------------- Final: out = x2 + ff + b2 (2-pass, clobber-safe) ----------
  {
    float b2v[4];
    #pragma unroll
    for (int nt = 0; nt < 4; ++nt) b2v[nt] = b2[w*64 + nt*16 + m];
    #pragma unroll
    for (int i = 0; i < 4; ++i){
      #pragma unroll
      for (int j = 0; j < 4; ++j) ff[i][j] = accfence(ff[i][j]);
    }
    // pass alpha: rows 0..31 (f32 writes land in bytes [0,32K) = dead h2 only)
    float x2a[2][4][4];
    #pragma unroll
    for (int rt = 0; rt < 2; ++rt)
      #pragma unroll
      for (int nt = 0; nt < 4; ++nt)
        #pragma unroll
        for (int j = 0; j < 4; ++j)
          x2a[rt][nt][j] = bf2f(x2buf[(rt*16 + 4*g + j)*256 + w*64 + nt*16 + m]);
    #pragma unroll
    for (int rt = 0; rt < 2; ++rt)
      #pragma unroll
      for (int nt = 0; nt < 4; ++nt)
        #pragma unroll
        for (int j = 0; j < 4; ++j)
          outb[(rt*16 + 4*g + j)*256 + w*64 + nt*16 + m] =
              x2a[rt][nt][j] + ff[rt][nt][j] + b2v[nt];
    // pass beta: read x2 rows 32..63 (bytes [48K,64K) - untouched so far), then
    // barrier, then write rows 32..63 (clobbers x2 region).
    float x2b[2][4][4];
    #pragma unroll
    for (int rt = 2; rt < 4; ++rt)
      #pragma unroll
      for (int nt = 0; nt < 4; ++nt)
        #pragma unroll
        for (int j = 0; j < 4; ++j)
          x2b[rt-2][nt][j] = bf2f(x2buf[(rt*16 + 4*g + j)*256 + w*64 + nt*16 + m]);
    __syncthreads();
    #pragma unroll
    for (int rt = 2; rt < 4; ++rt)
      #pragma unroll
      for (int nt = 0; nt < 4; ++nt)
        #pragma unroll
        for (int j = 0; j < 4; ++j)
          outb[(rt*16 + 4*g + j)*256 + w*64 + nt*16 + m] =
              x2b[rt-2][nt][j] + ff[rt][nt][j] + b2v[nt];
  }
}

extern "C" void kernel_launch(void* const* d_in, const int* in_sizes, int n_in,
                              void* d_out, int out_size, void* d_ws, size_t ws_size,
                              hipStream_t stream) {
  const float* x    = (const float*)d_in[0];
  const float* ln1g = (const float*)d_in[1];
  const float* ln1b = (const float*)d_in[2];
  const float* Wq   = (const float*)d_in[3];
  const float* Wk   = (const float*)d_in[4];
  const float* Wv   = (const float*)d_in[5];
  const float* Wp   = (const float*)d_in[6];
  const float* bpj  = (const float*)d_in[7];
  const float* ln2g = (const float*)d_in[8];
  const float* ln2b = (const float*)d_in[9];
  const float* W1   = (const float*)d_in[10];
  const float* b1   = (const float*)d_in[11];
  const float* W2   = (const float*)d_in[12];
  const float* b2   = (const float*)d_in[13];
  unsigned short* ws = (unsigned short*)d_ws;

  prep_w<<<3072, 256, 0, stream>>>(Wq, Wk, Wv, Wp, W1, W2, ws);
  blk_fwd<<<4096, 256, 0, stream>>>(x, ln1g, ln1b,
                                    ws, ws + 65536, ws + 131072, ws + 196608,
                                    bpj, ln2g, ln2b,
                                    ws + 262144, b1, ws + 524288, b2,
                                    (float*)d_out);
}

// Round 4
// 1324.166 us; speedup vs baseline: 2.7558x; 2.7558x over previous
//
#include <hip/hip_runtime.h>
#include <hip/hip_bf16.h>

// Fused transformer block, one 8-wave workgroup per batch element.
// LDS 64KB -> 2 blocks/CU = 16 waves/CU; __launch_bounds__(512,2): measured
// semantics of arg2 = min-blocks/CU -> VGPR cap 512/(2*8/4)=128 (round-2's
// (512,4) forced 64 VGPR and spilled; round-1's (256,2) gave 128, no spills).
// ws layout (bf16/ushort): [0,65536) WqT[h][d][c]; [65536,131072) WkT;
// [131072,196608) WvT; [196608,262144) WprojT[n][c]; [262144,524288) W1T[n][c];
// [524288,786432) W2T[n][k].  Requires ws_size >= 1572864 bytes.

typedef float v4f __attribute__((ext_vector_type(4)));
typedef int   v4i __attribute__((ext_vector_type(4)));
typedef float f4v __attribute__((ext_vector_type(4)));

#define DEV static __device__ __forceinline__

DEV unsigned short f2bf(float f){
  return __builtin_bit_cast(unsigned short, __float2bfloat16(f));
}

// bf16 MFMA via inline asm: layout-safe under consistent per-lane contiguous-8
// K fragments (A from [M][K] rows, B from [N][K] rows i.e. pre-transposed).
DEV v4f mfma16(v4i a, v4i b, v4f c){
  asm("v_mfma_f32_16x16x32_bf16 %0, %1, %2, %0" : "+v"(c) : "v"(a), "v"(b));
  return c;
}
// Hazard fence: asm MFMA is opaque to the hazard recognizer.
DEV v4f accfence(v4f c){
  asm("s_nop 7\n\ts_nop 3" : "+v"(c));
  return c;
}

// Swizzled LDS byte offsets (G4: XOR row bits into 16B-granule bits).
DEV int hoff(int r, int c){ return r*512 + ((c*2) ^ ((r & 7) << 4)); }  // [64][256] bf16
DEV int koff(int r, int c){ return r*128 + ((c*2) ^ ((r & 7) << 4)); }  // [*][64]  bf16

DEV float rsum64(float v){
  #pragma unroll
  for (int k = 1; k < 64; k <<= 1) v += __shfl_xor(v, k);
  return v;
}
DEV float rsum16(float v){
  #pragma unroll
  for (int k = 1; k < 16; k <<= 1) v += __shfl_xor(v, k);
  return v;
}
DEV float rmax16(float v){
  #pragma unroll
  for (int k = 1; k < 16; k <<= 1) v = fmaxf(v, __shfl_xor(v, k));
  return v;
}

__global__ void prep_w(const float* __restrict__ Wq, const float* __restrict__ Wk,
                       const float* __restrict__ Wv, const float* __restrict__ Wp,
                       const float* __restrict__ W1, const float* __restrict__ W2,
                       unsigned short* __restrict__ ws){
  int t = blockIdx.x * 256 + threadIdx.x;   // grid covers exactly 786432
  float v;
  if (t < 196608){
    int seg = t >> 16, r = t & 65535;
    int c = r & 255, d = (r >> 8) & 63, h = r >> 14;
    const float* W = (seg == 0) ? Wq : ((seg == 1) ? Wk : Wv);
    v = W[h*16384 + c*64 + d];
  } else if (t < 262144){
    int r = t - 196608; int n = r >> 8, c = r & 255;
    v = Wp[c*256 + n];
  } else if (t < 524288){
    int r = t - 262144; int n = r >> 8, c = r & 255;
    v = W1[c*1024 + n];
  } else {
    int r = t - 524288; int n = r >> 10, k = r & 1023;
    v = W2[k*256 + n];
  }
  ws[t] = f2bf(v);
}

__global__ __launch_bounds__(512, 2) void blk_fwd(
    const float* __restrict__ x,
    const float* __restrict__ ln1g, const float* __restrict__ ln1b,
    const unsigned short* __restrict__ wqT,
    const unsigned short* __restrict__ wkT,
    const unsigned short* __restrict__ wvT,
    const unsigned short* __restrict__ wpT,
    const float* __restrict__ bpj,
    const float* __restrict__ ln2g, const float* __restrict__ ln2b,
    const unsigned short* __restrict__ w1T,
    const float* __restrict__ b1,
    const unsigned short* __restrict__ w2T,
    const float* __restrict__ b2,
    float* __restrict__ out)
{
  __shared__ char smb[65536] __attribute__((aligned(16)));
  char* sm = smb;
  // LDS map. [0,32K): h then h2, [64][256] bf16 swizzled.
  // Phase B: QLS=q (P aliases q, same-wave), KLS=k, VTLS=v^T, ATLS=att (spare
  // 8KB -> removes per-head trailing barrier).  Phase C: PSUM/PSQ/MU2/RS2
  // alias ATLS (barrier after phase B protects).  Phase D: ALS [64][256]
  // aliases the whole upper 32KB.
  const int HLS = 0, QLS = 32768, KLS = 40960, VTLS = 49152, ATLS = 57344;
  const int ALS = 32768, PSUM = 57344, PSQ = 59392, MU2 = 61440, RS2 = 61696;

  const int b = blockIdx.x;
  const float* __restrict__ xb   = x   + (size_t)b * (64*256);
  float* __restrict__       outb = out + (size_t)b * (64*256);
  const int tid = threadIdx.x;
  const int w = tid >> 6, l = tid & 63, m = l & 15, g = l >> 4;
  const v4f zf = {0.f, 0.f, 0.f, 0.f};

  // ---------------- Phase A: LN1 -> h (bf16, LDS); float4 loads, u64 stores --------
  {
    f4v lg = *(const f4v*)(ln1g + 4*l);
    f4v lb = *(const f4v*)(ln1b + 4*l);
    #pragma unroll
    for (int rr = 0; rr < 8; ++rr){
      int r = w*8 + rr;
      f4v xv = *(const f4v*)(xb + r*256 + 4*l);
      float s = xv[0]+xv[1]+xv[2]+xv[3];
      float q = xv[0]*xv[0]+xv[1]*xv[1]+xv[2]*xv[2]+xv[3]*xv[3];
      s = rsum64(s); q = rsum64(q);
      float mu = s * (1.f/256.f);
      float rs = rsqrtf(q * (1.f/256.f) - mu*mu + 1e-6f);
      unsigned long long pk = 0;
      #pragma unroll
      for (int j = 0; j < 4; ++j){
        float hv = (xv[j] - mu) * rs * lg[j] + lb[j];
        pk |= (unsigned long long)f2bf(hv) << (16*j);
      }
      *(unsigned long long*)(sm + HLS + hoff(r, 4*l)) = pk;
    }
  }
  __syncthreads();

  // ---------------- Phase B: attention; sa accumulated in regs ----------------
  v4f sa[4][2];
  #pragma unroll
  for (int i = 0; i < 4; ++i){ sa[i][0] = zf; sa[i][1] = zf; }

  #pragma unroll 1
  for (int hh = 0; hh < 4; ++hh){
    // step 1: waves 0-3 compute q col-tiles, waves 4-7 compute k col-tiles
    {
      int ct = w & 3;
      const unsigned short* wsrc = ((w < 4) ? wqT : wkT) + hh*16384 + (ct*16 + m)*256;
      v4f acc[4];
      #pragma unroll
      for (int rt = 0; rt < 4; ++rt) acc[rt] = zf;
      #pragma unroll
      for (int ks = 0; ks < 8; ++ks){
        int k0 = ks*32 + 8*g;
        v4i bfr = *(const v4i*)(wsrc + k0);
        #pragma unroll
        for (int rt = 0; rt < 4; ++rt){
          v4i af = *(const v4i*)(sm + HLS + hoff(rt*16 + m, k0));
          acc[rt] = mfma16(af, bfr, acc[rt]);
        }
      }
      int base = (w < 4) ? QLS : KLS;
      #pragma unroll
      for (int rt = 0; rt < 4; ++rt){
        acc[rt] = accfence(acc[rt]);
        #pragma unroll
        for (int j = 0; j < 4; ++j)
          *(unsigned short*)(sm + base + koff(rt*16 + 4*g + j, ct*16 + m)) = f2bf(acc[rt][j]);
      }
    }
    __syncthreads();   // bar1: q,k ready

    // step 3: waves 0-3 compute v (-> v^T in LDS); waves 4-7 compute S+softmax -> P
    if (w < 4){
      const unsigned short* wsrc = wvT + hh*16384 + (w*16 + m)*256;
      v4f acc[4];
      #pragma unroll
      for (int rt = 0; rt < 4; ++rt) acc[rt] = zf;
      #pragma unroll
      for (int ks = 0; ks < 8; ++ks){
        int k0 = ks*32 + 8*g;
        v4i bfr = *(const v4i*)(wsrc + k0);
        #pragma unroll
        for (int rt = 0; rt < 4; ++rt){
          v4i af = *(const v4i*)(sm + HLS + hoff(rt*16 + m, k0));
          acc[rt] = mfma16(af, bfr, acc[rt]);
        }
      }
      #pragma unroll
      for (int rt = 0; rt < 4; ++rt){
        acc[rt] = accfence(acc[rt]);
        unsigned long long pk =
            (unsigned long long)f2bf(acc[rt][0])
          | ((unsigned long long)f2bf(acc[rt][1]) << 16)
          | ((unsigned long long)f2bf(acc[rt][2]) << 32)
          | ((unsigned long long)f2bf(acc[rt][3]) << 48);
        *(unsigned long long*)(sm + VTLS + koff(w*16 + m, rt*16 + 4*g)) = pk;  // V^T
      }
    } else {
      int srt = w - 4;
      v4f s4[4];
      #pragma unroll
      for (int nt = 0; nt < 4; ++nt) s4[nt] = zf;
      #pragma unroll
      for (int ks = 0; ks < 2; ++ks){
        int k0 = ks*32 + 8*g;
        v4i qf = *(const v4i*)(sm + QLS + koff(srt*16 + m, k0));
        #pragma unroll
        for (int nt = 0; nt < 4; ++nt){
          v4i kf = *(const v4i*)(sm + KLS + koff(nt*16 + m, k0));
          s4[nt] = mfma16(qf, kf, s4[nt]);
        }
      }
      #pragma unroll
      for (int nt = 0; nt < 4; ++nt) s4[nt] = accfence(s4[nt]);
      float mx[4] = {-3e38f, -3e38f, -3e38f, -3e38f};
      #pragma unroll
      for (int nt = 0; nt < 4; ++nt){
        #pragma unroll
        for (int j = 0; j < 4; ++j){
          int t = srt*16 + 4*g + j, ss = nt*16 + m;
          float z = s4[nt][j] * 0.125f;
          z = (ss <= t) ? z : -1e30f;
          s4[nt][j] = z;
          mx[j] = fmaxf(mx[j], z);
        }
      }
      #pragma unroll
      for (int j = 0; j < 4; ++j) mx[j] = rmax16(mx[j]);
      float sum[4] = {0.f, 0.f, 0.f, 0.f};
      #pragma unroll
      for (int nt = 0; nt < 4; ++nt){
        #pragma unroll
        for (int j = 0; j < 4; ++j){
          float p = __expf(s4[nt][j] - mx[j]);
          s4[nt][j] = p;
          sum[j] += p;
        }
      }
      #pragma unroll
      for (int j = 0; j < 4; ++j) sum[j] = 1.f / rsum16(sum[j]);
      #pragma unroll
      for (int nt = 0; nt < 4; ++nt){
        #pragma unroll
        for (int j = 0; j < 4; ++j)
          *(unsigned short*)(sm + QLS + koff(srt*16 + 4*g + j, nt*16 + m)) =
              f2bf(s4[nt][j] * sum[j]);   // P overwrites this wave's own q rows
      }
    }
    __syncthreads();   // bar2: P, v^T ready

    // step 5: waves 0-3 compute att row-tile w = P V; store into ATLS (spare)
    if (w < 4){
      v4f av[4];
      #pragma unroll
      for (int nt = 0; nt < 4; ++nt) av[nt] = zf;
      #pragma unroll
      for (int ks = 0; ks < 2; ++ks){
        int k0 = ks*32 + 8*g;
        v4i pf = *(const v4i*)(sm + QLS + koff(w*16 + m, k0));
        #pragma unroll
        for (int nt = 0; nt < 4; ++nt){
          v4i vf = *(const v4i*)(sm + VTLS + koff(nt*16 + m, k0));
          av[nt] = mfma16(pf, vf, av[nt]);
        }
      }
      #pragma unroll
      for (int nt = 0; nt < 4; ++nt) av[nt] = accfence(av[nt]);
      #pragma unroll
      for (int nt = 0; nt < 4; ++nt){
        #pragma unroll
        for (int j = 0; j < 4; ++j)
          *(unsigned short*)(sm + ATLS + koff(w*16 + 4*g + j, nt*16 + m)) = f2bf(av[nt][j]);
      }
    }
    __syncthreads();   // bar3: att ready

    // step 7: sa += att_head @ Wproj[64*hh:, :]; wave w owns cols w*32..w*32+31.
    // No trailing barrier: next head's q/k writes (QLS/KLS) are dead here, and
    // ATLS is next written only after next bar2 -> all waves passed this point.
    #pragma unroll
    for (int ks = 0; ks < 2; ++ks){
      int k0 = ks*32 + 8*g;
      v4i af2[4];
      #pragma unroll
      for (int rt = 0; rt < 4; ++rt) af2[rt] = *(const v4i*)(sm + ATLS + koff(rt*16 + m, k0));
      #pragma unroll
      for (int nt = 0; nt < 2; ++nt){
        v4i bp = *(const v4i*)(wpT + (w*32 + nt*16 + m)*256 + hh*64 + k0);
        #pragma unroll
        for (int rt = 0; rt < 4; ++rt) sa[rt][nt] = mfma16(af2[rt], bp, sa[rt][nt]);
      }
    }
  }
  __syncthreads();   // protect PSUM/PSQ (alias ATLS) from stragglers' proj reads

  // ---------------- Phase C: x2 = x + sa + bproj; LN2 -> h2 ----------------
  {
    #pragma unroll
    for (int i = 0; i < 4; ++i){ sa[i][0] = accfence(sa[i][0]); sa[i][1] = accfence(sa[i][1]); }
    float bp2[2], lg2[2], lb2[2];
    #pragma unroll
    for (int nt = 0; nt < 2; ++nt){
      int cc = w*32 + nt*16 + m;
      bp2[nt] = bpj[cc]; lg2[nt] = ln2g[cc]; lb2[nt] = ln2b[cc];
    }
    #pragma unroll
    for (int rt = 0; rt < 4; ++rt){
      #pragma unroll
      for (int j = 0; j < 4; ++j){
        int row = rt*16 + 4*g + j;
        #pragma unroll
        for (int nt = 0; nt < 2; ++nt){
          int col = w*32 + nt*16 + m;
          float v = xb[row*256 + col] + sa[rt][nt][j] + bp2[nt];
          sa[rt][nt][j] = v;
          outb[row*256 + col] = v;     // park x2 in d_out; re-read at final residual
        }
      }
    }
    #pragma unroll
    for (int rt = 0; rt < 4; ++rt){
      #pragma unroll
      for (int j = 0; j < 4; ++j){
        float s = 0.f, q = 0.f;
        #pragma unroll
        for (int nt = 0; nt < 2; ++nt){ float v = sa[rt][nt][j]; s += v; q += v*v; }
        s = rsum16(s); q = rsum16(q);
        if (m == 0){
          int row = rt*16 + 4*g + j;
          *(float*)(sm + PSUM + (w*64 + row)*4) = s;
          *(float*)(sm + PSQ  + (w*64 + row)*4) = q;
        }
      }
    }
    __syncthreads();
    if (tid < 64){
      float s = 0.f, q = 0.f;
      #pragma unroll
      for (int i = 0; i < 8; ++i){
        s += *(const float*)(sm + PSUM + (i*64 + tid)*4);
        q += *(const float*)(sm + PSQ  + (i*64 + tid)*4);
      }
      float mu = s * (1.f/256.f);
      float rs = rsqrtf(q * (1.f/256.f) - mu*mu + 1e-6f);
      *(float*)(sm + MU2 + tid*4) = mu;
      *(float*)(sm + RS2 + tid*4) = rs;
    }
    __syncthreads();
    #pragma unroll
    for (int rt = 0; rt < 4; ++rt){
      #pragma unroll
      for (int j = 0; j < 4; ++j){
        int row = rt*16 + 4*g + j;
        float mu = *(const float*)(sm + MU2 + row*4);
        float rs = *(const float*)(sm + RS2 + row*4);
        #pragma unroll
        for (int nt = 0; nt < 2; ++nt){
          int col = w*32 + nt*16 + m;
          float h2 = (sa[rt][nt][j] - mu) * rs * lg2[nt] + lb2[nt];
          *(unsigned short*)(sm + HLS + hoff(row, col)) = f2bf(h2);
        }
      }
    }
  }
  __syncthreads();

  // ---------------- Phase D: MLP, K-chunked (256); ff accumulates in regs ----------
  v4f ff[4][2];
  #pragma unroll
  for (int i = 0; i < 4; ++i){ ff[i][0] = zf; ff[i][1] = zf; }

  #pragma unroll 1
  for (int ch = 0; ch < 4; ++ch){
    v4f a1[4][2];
    #pragma unroll
    for (int i = 0; i < 4; ++i){ a1[i][0] = zf; a1[i][1] = zf; }
    #pragma unroll
    for (int ks = 0; ks < 8; ++ks){
      int k0 = ks*32 + 8*g;
      v4i af[4];
      #pragma unroll
      for (int rt = 0; rt < 4; ++rt) af[rt] = *(const v4i*)(sm + HLS + hoff(rt*16 + m, k0));
      #pragma unroll
      for (int nt = 0; nt < 2; ++nt){
        v4i bw = *(const v4i*)(w1T + (ch*256 + w*32 + nt*16 + m)*256 + k0);
        #pragma unroll
        for (int rt = 0; rt < 4; ++rt) a1[rt][nt] = mfma16(af[rt], bw, a1[rt][nt]);
      }
    }
    float b1v[2];
    #pragma unroll
    for (int nt = 0; nt < 2; ++nt) b1v[nt] = b1[ch*256 + w*32 + nt*16 + m];
    #pragma unroll
    for (int i = 0; i < 4; ++i){ a1[i][0] = accfence(a1[i][0]); a1[i][1] = accfence(a1[i][1]); }
    #pragma unroll
    for (int rt = 0; rt < 4; ++rt){
      #pragma unroll
      for (int j = 0; j < 4; ++j){
        int row = rt*16 + 4*g + j;
        #pragma unroll
        for (int nt = 0; nt < 2; ++nt){
          int cc = w*32 + nt*16 + m;
          float v = fmaxf(a1[rt][nt][j] + b1v[nt], 0.f);
          *(unsigned short*)(sm + ALS + hoff(row, cc)) = f2bf(v);
        }
      }
    }
    __syncthreads();
    #pragma unroll
    for (int ks = 0; ks < 8; ++ks){
      int k0 = ks*32 + 8*g;
      v4i af[4];
      #pragma unroll
      for (int rt = 0; rt < 4; ++rt) af[rt] = *(const v4i*)(sm + ALS + hoff(rt*16 + m, k0));
      #pragma unroll
      for (int nt = 0; nt < 2; ++nt){
        v4i bw = *(const v4i*)(w2T + (w*32 + nt*16 + m)*1024 + ch*256 + k0);
        #pragma unroll
        for (int rt = 0; rt < 4; ++rt) ff[rt][nt] = mfma16(af[rt], bw, ff[rt][nt]);
      }
    }
    __syncthreads();
  }

  {
    float b2v[2];
    #pragma unroll
    for (int nt = 0; nt < 2; ++nt) b2v[nt] = b2[w*32 + nt*16 + m];
    #pragma unroll
    for (int i = 0; i < 4; ++i){ ff[i][0] = accfence(ff[i][0]); ff[i][1] = accfence(ff[i][1]); }
    #pragma unroll
    for (int rt = 0; rt < 4; ++rt){
      #pragma unroll
      for (int j = 0; j < 4; ++j){
        int row = rt*16 + 4*g + j;
        #pragma unroll
        for (int nt = 0; nt < 2; ++nt){
          int col = w*32 + nt*16 + m;
          outb[row*256 + col] += ff[rt][nt][j] + b2v[nt];
        }
      }
    }
  }
}

extern "C" void kernel_launch(void* const* d_in, const int* in_sizes, int n_in,
                              void* d_out, int out_size, void* d_ws, size_t ws_size,
                              hipStream_t stream) {
  const float* x    = (const float*)d_in[0];
  const float* ln1g = (const float*)d_in[1];
  const float* ln1b = (const float*)d_in[2];
  const float* Wq   = (const float*)d_in[3];
  const float* Wk   = (const float*)d_in[4];
  const float* Wv   = (const float*)d_in[5];
  const float* Wp   = (const float*)d_in[6];
  const float* bpj  = (const float*)d_in[7];
  const float* ln2g = (const float*)d_in[8];
  const float* ln2b = (const float*)d_in[9];
  const float* W1   = (const float*)d_in[10];
  const float* b1   = (const float*)d_in[11];
  const float* W2   = (const float*)d_in[12];
  const float* b2   = (const float*)d_in[13];
  unsigned short* ws = (unsigned short*)d_ws;

  prep_w<<<3072, 256, 0, stream>>>(Wq, Wk, Wv, Wp, W1, W2, ws);
  blk_fwd<<<4096, 512, 0, stream>>>(x, ln1g, ln1b,
                                    ws, ws + 65536, ws + 131072, ws + 196608,
                                    bpj, ln2g, ln2b,
                                    ws + 262144, b1, ws + 524288, b2,
                                    (float*)d_out);
}

// Round 5
// 1282.430 us; speedup vs baseline: 2.8455x; 1.0325x over previous
//
#include <hip/hip_runtime.h>
#include <hip/hip_bf16.h>

// Fused transformer block, one 16-wave (1024-thr) workgroup per batch element.
// Thin per-wave tiles (16 output cols/wave) keep VGPR ~<=100 so all 16 waves
// are resident (4 waves/SIMD) -- empirical law from R1-R4: budget ~256/(waves
// per SIMD). LDS 104KB dynamic (1 block/CU).
// ws layout (bf16/ushort): [0,65536) WqT[h][d][c]; [65536,131072) WkT;
// [131072,196608) WvT; [196608,262144) WprojT[n][c]; [262144,524288) W1T[n][c];
// [524288,786432) W2T[n][k].  Requires ws_size >= 1572864 bytes.

typedef float v4f __attribute__((ext_vector_type(4)));
typedef int   v4i __attribute__((ext_vector_type(4)));
typedef float f4v __attribute__((ext_vector_type(4)));

#define DEV static __device__ __forceinline__

DEV unsigned short f2bf(float f){
  return __builtin_bit_cast(unsigned short, __float2bfloat16(f));
}

// bf16 MFMA via inline asm: layout-safe under consistent per-lane contiguous-8
// K fragments (A from [M][K] rows, B from [N][K] rows i.e. pre-transposed).
DEV v4f mfma16(v4i a, v4i b, v4f c){
  asm("v_mfma_f32_16x16x32_bf16 %0, %1, %2, %0" : "+v"(c) : "v"(a), "v"(b));
  return c;
}
// Hazard fence: asm MFMA is opaque to the hazard recognizer.
DEV v4f accfence(v4f c){
  asm("s_nop 7\n\ts_nop 3" : "+v"(c));
  return c;
}

// Swizzled LDS byte offsets (G4: XOR row bits into 16B-granule bits).
DEV int hoff(int r, int c){ return r*512 + ((c*2) ^ ((r & 7) << 4)); }  // [64][256] bf16
DEV int koff(int r, int c){ return r*128 + ((c*2) ^ ((r & 7) << 4)); }  // [*][64]  bf16

DEV unsigned long long pack4(v4f v){
  return (unsigned long long)f2bf(v[0])
       | ((unsigned long long)f2bf(v[1]) << 16)
       | ((unsigned long long)f2bf(v[2]) << 32)
       | ((unsigned long long)f2bf(v[3]) << 48);
}

DEV float rsum64(float v){
  #pragma unroll
  for (int k = 1; k < 64; k <<= 1) v += __shfl_xor(v, k);
  return v;
}
DEV float rmax64(float v){
  #pragma unroll
  for (int k = 1; k < 64; k <<= 1) v = fmaxf(v, __shfl_xor(v, k));
  return v;
}
DEV float rsum16(float v){
  #pragma unroll
  for (int k = 1; k < 16; k <<= 1) v += __shfl_xor(v, k);
  return v;
}

__global__ void prep_w(const float* __restrict__ Wq, const float* __restrict__ Wk,
                       const float* __restrict__ Wv, const float* __restrict__ Wp,
                       const float* __restrict__ W1, const float* __restrict__ W2,
                       unsigned short* __restrict__ ws){
  int t = blockIdx.x * 256 + threadIdx.x;   // grid covers exactly 786432
  float v;
  if (t < 196608){
    int seg = t >> 16, r = t & 65535;
    int c = r & 255, d = (r >> 8) & 63, h = r >> 14;
    const float* W = (seg == 0) ? Wq : ((seg == 1) ? Wk : Wv);
    v = W[h*16384 + c*64 + d];
  } else if (t < 262144){
    int r = t - 196608; int n = r >> 8, c = r & 255;
    v = Wp[c*256 + n];
  } else if (t < 524288){
    int r = t - 262144; int n = r >> 8, c = r & 255;
    v = W1[c*1024 + n];
  } else {
    int r = t - 524288; int n = r >> 10, k = r & 1023;
    v = W2[k*256 + n];
  }
  ws[t] = f2bf(v);
}

// LDS map (bytes), dynamic 106752 total:
//   HLS  @0      [64][256] bf16 swz : h, later h2
//   ATT  @32768  [64][256] bf16 swz : att concat over heads; phase D act chunk
//   QP   @65536  [64][64]  bf16 swz : q, then P (q dead after S tiles + bar)
//   KT   @73728  [64][64]  bf16 swz : k
//   VT   @81920  [64][64]  bf16 swz : v^T rows=d
//   SB   @90112  [64][65]  f32      : raw S tiles (also phase-C scratch alias)
#define LDS_BYTES 106752

__global__ __launch_bounds__(1024) void blk_fwd(
    const float* __restrict__ x,
    const float* __restrict__ ln1g, const float* __restrict__ ln1b,
    const unsigned short* __restrict__ wqT,
    const unsigned short* __restrict__ wkT,
    const unsigned short* __restrict__ wvT,
    const unsigned short* __restrict__ wpT,
    const float* __restrict__ bpj,
    const float* __restrict__ ln2g, const float* __restrict__ ln2b,
    const unsigned short* __restrict__ w1T,
    const float* __restrict__ b1,
    const unsigned short* __restrict__ w2T,
    const float* __restrict__ b2,
    float* __restrict__ out)
{
  extern __shared__ char sm[];
  const int HLS = 0, ATT = 32768, QP = 65536, KT = 73728, VT = 81920, SB = 90112;
  const int PSUM = SB, PSQ = SB + 4096, MU2 = SB + 8192, RS2 = SB + 8448;

  const int b = blockIdx.x;
  const float* __restrict__ xb   = x   + (size_t)b * (64*256);
  float* __restrict__       outb = out + (size_t)b * (64*256);
  const int tid = threadIdx.x;
  const int w = tid >> 6, l = tid & 63, m = l & 15, g = l >> 4;
  const v4f zf = {0.f, 0.f, 0.f, 0.f};

  // ---------------- Phase A: LN1 -> h (bf16, LDS); 4 rows per wave ------------
  {
    f4v lg = *(const f4v*)(ln1g + 4*l);
    f4v lb = *(const f4v*)(ln1b + 4*l);
    #pragma unroll
    for (int rr = 0; rr < 4; ++rr){
      int r = w*4 + rr;
      f4v xv = *(const f4v*)(xb + r*256 + 4*l);
      float s = xv[0]+xv[1]+xv[2]+xv[3];
      float q = xv[0]*xv[0]+xv[1]*xv[1]+xv[2]*xv[2]+xv[3]*xv[3];
      s = rsum64(s); q = rsum64(q);
      float mu = s * (1.f/256.f);
      float rs = rsqrtf(q * (1.f/256.f) - mu*mu + 1e-6f);
      unsigned long long pk = 0;
      #pragma unroll
      for (int j = 0; j < 4; ++j){
        float hv = (xv[j] - mu) * rs * lg[j] + lb[j];
        pk |= (unsigned long long)f2bf(hv) << (16*j);
      }
      *(unsigned long long*)(sm + HLS + hoff(r, 4*l)) = pk;
    }
  }
  __syncthreads();

  // ---------------- Phase B: attention, att concat into ATT -------------------
  #pragma unroll 1
  for (int hh = 0; hh < 4; ++hh){
    // step 1: 12 waves compute q/k/v 16-col stripes (waves 12-15 idle)
    if (w < 12){
      int tsel = w >> 2, ct = w & 3;
      const unsigned short* wsrc =
          (tsel == 0 ? wqT : (tsel == 1 ? wkT : wvT)) + hh*16384 + (ct*16 + m)*256;
      v4f acc[4] = {zf, zf, zf, zf};
      #pragma unroll
      for (int ks = 0; ks < 8; ++ks){
        int k0 = ks*32 + 8*g;
        v4i bfr = *(const v4i*)(wsrc + k0);
        #pragma unroll
        for (int rt = 0; rt < 4; ++rt){
          v4i af = *(const v4i*)(sm + HLS + hoff(rt*16 + m, k0));
          acc[rt] = mfma16(af, bfr, acc[rt]);
        }
      }
      if (tsel < 2){
        int base = (tsel == 0) ? QP : KT;
        #pragma unroll
        for (int rt = 0; rt < 4; ++rt){
          acc[rt] = accfence(acc[rt]);
          #pragma unroll
          for (int j = 0; j < 4; ++j)
            *(unsigned short*)(sm + base + koff(rt*16 + 4*g + j, ct*16 + m)) =
                f2bf(acc[rt][j]);
        }
      } else {
        #pragma unroll
        for (int rt = 0; rt < 4; ++rt){
          acc[rt] = accfence(acc[rt]);
          *(unsigned long long*)(sm + VT + koff(ct*16 + m, rt*16 + 4*g)) = pack4(acc[rt]);
        }
      }
    }
    __syncthreads();

    // step 2: all 16 waves: one 16x16 S-tile each -> SB (f32, masked+scaled)
    {
      int rt = w >> 2, nt = w & 3;
      v4f s4 = zf;
      #pragma unroll
      for (int ks = 0; ks < 2; ++ks){
        int k0 = ks*32 + 8*g;
        v4i qf = *(const v4i*)(sm + QP + koff(rt*16 + m, k0));
        v4i kf = *(const v4i*)(sm + KT + koff(nt*16 + m, k0));
        s4 = mfma16(qf, kf, s4);
      }
      s4 = accfence(s4);
      #pragma unroll
      for (int j = 0; j < 4; ++j){
        int t = rt*16 + 4*g + j, ss = nt*16 + m;
        float z = s4[j] * 0.125f;
        z = (ss <= t) ? z : -1e30f;
        *(float*)(sm + SB + t*260 + ss*4) = z;
      }
    }
    __syncthreads();

    // step 3: softmax, 4 rows per wave, full-wave reduce; P overwrites q (QP)
    {
      #pragma unroll
      for (int rr = 0; rr < 4; ++rr){
        int r = w*4 + rr;
        float v = *(const float*)(sm + SB + r*260 + l*4);
        float mx = rmax64(v);
        float p = __expf(v - mx);
        float s = rsum64(p);
        p = p * (1.f / s);
        *(unsigned short*)(sm + QP + koff(r, l)) = f2bf(p);
      }
    }
    __syncthreads();

    // step 4: all 16 waves: one 16x16 PV-tile each -> ATT[., hh*64 + .]
    {
      int rt = w >> 2, nt = w & 3;
      v4f av = zf;
      #pragma unroll
      for (int ks = 0; ks < 2; ++ks){
        int k0 = ks*32 + 8*g;
        v4i pf = *(const v4i*)(sm + QP + koff(rt*16 + m, k0));
        v4i vf = *(const v4i*)(sm + VT + koff(nt*16 + m, k0));
        av = mfma16(pf, vf, av);
      }
      av = accfence(av);
      #pragma unroll
      for (int j = 0; j < 4; ++j)
        *(unsigned short*)(sm + ATT + hoff(rt*16 + 4*g + j, hh*64 + nt*16 + m)) =
            f2bf(av[j]);
    }
    __syncthreads();
  }

  // ---------------- proj: sa = att_concat @ WprojT; 16 cols per wave ----------
  v4f sa[4] = {zf, zf, zf, zf};
  {
    const unsigned short* bpp = wpT + (w*16 + m)*256;
    #pragma unroll
    for (int ks = 0; ks < 8; ++ks){
      int k0 = ks*32 + 8*g;
      v4i bp = *(const v4i*)(bpp + k0);
      #pragma unroll
      for (int rt = 0; rt < 4; ++rt){
        v4i af = *(const v4i*)(sm + ATT + hoff(rt*16 + m, k0));
        sa[rt] = mfma16(af, bp, sa[rt]);
      }
    }
    #pragma unroll
    for (int rt = 0; rt < 4; ++rt) sa[rt] = accfence(sa[rt]);
  }

  // ---------------- Phase C: x2 = x + sa + bproj (f32 -> d_out); LN2 -> h2 ----
  {
    int c = w*16 + m;
    float bp1 = bpj[c], lg2 = ln2g[c], lb2 = ln2b[c];
    #pragma unroll
    for (int rt = 0; rt < 4; ++rt){
      #pragma unroll
      for (int j = 0; j < 4; ++j){
        int row = rt*16 + 4*g + j;
        float v = xb[row*256 + c] + sa[rt][j] + bp1;
        sa[rt][j] = v;
        outb[row*256 + c] = v;          // park x2 f32; re-read at final residual
      }
    }
    #pragma unroll
    for (int rt = 0; rt < 4; ++rt){
      #pragma unroll
      for (int j = 0; j < 4; ++j){
        float s = rsum16(sa[rt][j]);
        float q = rsum16(sa[rt][j]*sa[rt][j]);
        if (m == 0){
          int row = rt*16 + 4*g + j;
          *(float*)(sm + PSUM + row*64 + w*4) = s;
          *(float*)(sm + PSQ  + row*64 + w*4) = q;
        }
      }
    }
    __syncthreads();
    if (tid < 64){
      float s = 0.f, q = 0.f;
      #pragma unroll
      for (int i = 0; i < 16; ++i){
        s += *(const float*)(sm + PSUM + tid*64 + i*4);
        q += *(const float*)(sm + PSQ  + tid*64 + i*4);
      }
      float mu = s * (1.f/256.f);
      float rs = rsqrtf(q * (1.f/256.f) - mu*mu + 1e-6f);
      *(float*)(sm + MU2 + tid*4) = mu;
      *(float*)(sm + RS2 + tid*4) = rs;
    }
    __syncthreads();
    #pragma unroll
    for (int rt = 0; rt < 4; ++rt){
      #pragma unroll
      for (int j = 0; j < 4; ++j){
        int row = rt*16 + 4*g + j;
        float mu = *(const float*)(sm + MU2 + row*4);
        float rs = *(const float*)(sm + RS2 + row*4);
        float h2 = (sa[rt][j] - mu) * rs * lg2 + lb2;
        *(unsigned short*)(sm + HLS + hoff(row, c)) = f2bf(h2);  // h dead
      }
    }
  }
  __syncthreads();

  // ---------------- Phase D: MLP, 4 chunks of 256; 16 cols per wave -----------
  v4f ff[4] = {zf, zf, zf, zf};
  #pragma unroll 1
  for (int ch = 0; ch < 4; ++ch){
    v4f a1[4] = {zf, zf, zf, zf};
    const unsigned short* w1p = w1T + (ch*256 + w*16 + m)*256;
    #pragma unroll
    for (int ks = 0; ks < 8; ++ks){
      int k0 = ks*32 + 8*g;
      v4i bw = *(const v4i*)(w1p + k0);
      #pragma unroll
      for (int rt = 0; rt < 4; ++rt){
        v4i af = *(const v4i*)(sm + HLS + hoff(rt*16 + m, k0));
        a1[rt] = mfma16(af, bw, a1[rt]);
      }
    }
    float b1v = b1[ch*256 + w*16 + m];
    #pragma unroll
    for (int rt = 0; rt < 4; ++rt){
      a1[rt] = accfence(a1[rt]);
      #pragma unroll
      for (int j = 0; j < 4; ++j){
        int row = rt*16 + 4*g + j;
        float v = fmaxf(a1[rt][j] + b1v, 0.f);
        *(unsigned short*)(sm + ATT + hoff(row, w*16 + m)) = f2bf(v);  // act chunk
      }
    }
    __syncthreads();
    const unsigned short* w2p = w2T + (w*16 + m)*1024 + ch*256;
    #pragma unroll
    for (int ks = 0; ks < 8; ++ks){
      int k0 = ks*32 + 8*g;
      v4i bw = *(const v4i*)(w2p + k0);
      #pragma unroll
      for (int rt = 0; rt < 4; ++rt){
        v4i af = *(const v4i*)(sm + ATT + hoff(rt*16 + m, k0));
        ff[rt] = mfma16(af, bw, ff[rt]);
      }
    }
    __syncthreads();   // protect act chunk before next GEMM1 overwrite
  }

  // ---------------- Final: out = x2 + ff + b2 (RMW of parked f32 x2) ----------
  {
    int c = w*16 + m;
    float b2v = b2[c];
    #pragma unroll
    for (int rt = 0; rt < 4; ++rt){
      ff[rt] = accfence(ff[rt]);
      #pragma unroll
      for (int j = 0; j < 4; ++j){
        int row = rt*16 + 4*g + j;
        outb[row*256 + c] += ff[rt][j] + b2v;
      }
    }
  }
}

extern "C" void kernel_launch(void* const* d_in, const int* in_sizes, int n_in,
                              void* d_out, int out_size, void* d_ws, size_t ws_size,
                              hipStream_t stream) {
  const float* x    = (const float*)d_in[0];
  const float* ln1g = (const float*)d_in[1];
  const float* ln1b = (const float*)d_in[2];
  const float* Wq   = (const float*)d_in[3];
  const float* Wk   = (const float*)d_in[4];
  const float* Wv   = (const float*)d_in[5];
  const float* Wp   = (const float*)d_in[6];
  const float* bpj  = (const float*)d_in[7];
  const float* ln2g = (const float*)d_in[8];
  const float* ln2b = (const float*)d_in[9];
  const float* W1   = (const float*)d_in[10];
  const float* b1   = (const float*)d_in[11];
  const float* W2   = (const float*)d_in[12];
  const float* b2   = (const float*)d_in[13];
  unsigned short* ws = (unsigned short*)d_ws;

  static bool attr_set = false;
  if (!attr_set){
    hipFuncSetAttribute((const void*)blk_fwd,
                        hipFuncAttributeMaxDynamicSharedMemorySize, LDS_BYTES);
    attr_set = true;
  }

  prep_w<<<3072, 256, 0, stream>>>(Wq, Wk, Wv, Wp, W1, W2, ws);
  blk_fwd<<<4096, 1024, LDS_BYTES, stream>>>(x, ln1g, ln1b,
                                    ws, ws + 65536, ws + 131072, ws + 196608,
                                    bpj, ln2g, ln2b,
                                    ws + 262144, b1, ws + 524288, b2,
                                    (float*)d_out);
}